// Round 1
// baseline (728.387 us; speedup 1.0000x reference)
//
#include <hip/hip_runtime.h>
#include <math.h>

// Problem constants (match reference)
#define FEAT   128
#define NBANK  1000000
#define KP1    4097            // K_NEG + 1
#define BATCH  256
#define INV_T  2.0f            // 1 / T, T = 0.5
#define EPS_N  1e-7f

// Output layout (floats, concatenated in return order)
constexpr size_t TOTP   = (size_t)BATCH * KP1;        // 1048832 per score output
constexpr size_t O_OUTL = 0;
constexpr size_t O_OUTA = TOTP;                       // 1048832
constexpr size_t O_MEML = 2 * TOTP;                   // 2097664
constexpr size_t O_MEMA = O_MEML + (size_t)NBANK * FEAT; // 130097664

// Scoring tiling
constexpr int KCHUNK = 64;                            // k's per block (4 waves x 16)
constexpr int NCHUNK = (KP1 + KCHUNK - 1) / KCHUNK;   // 65
constexpr int NPART  = BATCH * NCHUNK;                // 16640 partial-sum slots

// Workspace layout (floats)
constexpr size_t WS_LN    = 0;
constexpr size_t WS_ABN   = WS_LN + (size_t)BATCH * FEAT;   // 32768
constexpr size_t WS_PARTL = WS_ABN + (size_t)BATCH * FEAT;  // 65536
constexpr size_t WS_PARTA = WS_PARTL + NPART;               // 82176
constexpr size_t WS_INVZ  = WS_PARTA + NPART;               // 98816 (+2)

// ---------------------------------------------------------------------------
// 1) L2-normalize l and ab rows:  x / (sqrt(sum x^2) + eps)
//    grid: 512 blocks (0..255 -> l, 256..511 -> ab), 64 threads (1 wave)
// ---------------------------------------------------------------------------
__global__ void norm_kernel(const float* __restrict__ l,
                            const float* __restrict__ ab,
                            float* __restrict__ ws) {
    int b    = blockIdx.x;
    int lane = threadIdx.x;           // 0..63, 2 floats per lane
    const float* src;
    float*       dst;
    if (b < BATCH) { src = l  + (size_t)b * FEAT;            dst = ws + WS_LN  + (size_t)b * FEAT; }
    else           { src = ab + (size_t)(b - BATCH) * FEAT;  dst = ws + WS_ABN + (size_t)(b - BATCH) * FEAT; }
    float2 v = *(const float2*)(src + 2 * lane);
    float  ss = v.x * v.x + v.y * v.y;
    #pragma unroll
    for (int m = 1; m < 64; m <<= 1) ss += __shfl_xor(ss, m, 64);
    float inv = 1.0f / (sqrtf(ss) + EPS_N);
    ((float2*)dst)[lane] = make_float2(v.x * inv, v.y * inv);
}

// ---------------------------------------------------------------------------
// 2) Fused scoring: for each (b,k) gather BOTH bank rows at idx[b,k], compute
//    exp(dot * 2) for out_l (mem_ab . ln) and out_ab (mem_l . abn).
//    Writes unscaled P into d_out, per-block partial sums into ws.
//    grid: (BATCH, NCHUNK) x 256 threads (4 waves x 16 k each)
// ---------------------------------------------------------------------------
__global__ __launch_bounds__(256) void score_kernel(
        const float* __restrict__ mem_l, const float* __restrict__ mem_ab,
        const int*   __restrict__ idx,
        const float* __restrict__ ws_in,   // ln/abn
        float* __restrict__ out,
        float* __restrict__ part_l, float* __restrict__ part_ab) {
    int b     = blockIdx.x;
    int chunk = blockIdx.y;
    int wave  = threadIdx.x >> 6;
    int lane  = threadIdx.x & 63;

    float2 lv = *(const float2*)(ws_in + WS_LN  + (size_t)b * FEAT + 2 * lane);
    float2 av = *(const float2*)(ws_in + WS_ABN + (size_t)b * FEAT + 2 * lane);

    float sum_l = 0.f, sum_ab = 0.f;
    int k0 = chunk * KCHUNK + wave * (KCHUNK / 4);
    #pragma unroll 4
    for (int i = 0; i < KCHUNK / 4; ++i) {
        int k = k0 + i;
        if (k >= KP1) break;
        int row = idx[(size_t)b * KP1 + k];
        float2 wa = ((const float2*)(mem_ab + (size_t)row * FEAT))[lane];
        float2 wl = ((const float2*)(mem_l  + (size_t)row * FEAT))[lane];
        float dl  = wa.x * lv.x + wa.y * lv.y;   // -> P_l
        float dab = wl.x * av.x + wl.y * av.y;   // -> P_ab
        #pragma unroll
        for (int m = 1; m < 64; m <<= 1) {
            dl  += __shfl_xor(dl,  m, 64);
            dab += __shfl_xor(dab, m, 64);
        }
        float pl  = __expf(dl * INV_T) ;
        float pab = __expf(dab * INV_T);
        // use precise expf for accuracy (threshold generous, but cheap here)
        pl  = expf(dl * INV_T);
        pab = expf(dab * INV_T);
        if (lane == 0) {
            out[O_OUTL + (size_t)b * KP1 + k] = pl;
            out[O_OUTA + (size_t)b * KP1 + k] = pab;
        }
        sum_l += pl; sum_ab += pab;   // identical across lanes post-reduce
    }
    __shared__ float s[8];
    if (lane == 0) { s[wave] = sum_l; s[4 + wave] = sum_ab; }
    __syncthreads();
    if (threadIdx.x == 0) {
        part_l[(size_t)b * NCHUNK + chunk]  = s[0] + s[1] + s[2] + s[3];
        part_ab[(size_t)b * NCHUNK + chunk] = s[4] + s[5] + s[6] + s[7];
    }
}

// ---------------------------------------------------------------------------
// 3) Deterministic reduction of partials -> 1/Z for both outputs
//    1 block, 256 threads, fixed-order tree reduce.
// ---------------------------------------------------------------------------
__global__ void zreduce_kernel(const float* __restrict__ part_l,
                               const float* __restrict__ part_ab,
                               float* __restrict__ invz) {
    __shared__ float sl[256], sa[256];
    float a = 0.f, b = 0.f;
    for (int i = threadIdx.x; i < NPART; i += 256) { a += part_l[i]; b += part_ab[i]; }
    sl[threadIdx.x] = a; sa[threadIdx.x] = b;
    __syncthreads();
    for (int s = 128; s > 0; s >>= 1) {
        if (threadIdx.x < (unsigned)s) {
            sl[threadIdx.x] += sl[threadIdx.x + s];
            sa[threadIdx.x] += sa[threadIdx.x + s];
        }
        __syncthreads();
    }
    if (threadIdx.x == 0) {
        float count = (float)TOTP;
        // out = P / Z, Z = (sum/count) * NBANK  ->  invZ = count / (sum * NBANK)
        invz[0] = count / (sl[0] * (float)NBANK);
        invz[1] = count / (sa[0] * (float)NBANK);
    }
}

// ---------------------------------------------------------------------------
// 4) Scale both P regions in place by 1/Z
// ---------------------------------------------------------------------------
__global__ void scale_kernel(float* __restrict__ out, const float* __restrict__ invz) {
    float zl = invz[0], za = invz[1];
    size_t stride = (size_t)gridDim.x * blockDim.x;
    for (size_t i = (size_t)blockIdx.x * blockDim.x + threadIdx.x; i < TOTP; i += stride) {
        out[O_OUTL + i] *= zl;
        out[O_OUTA + i] *= za;
    }
}

// ---------------------------------------------------------------------------
// 5) Copy both memory banks into d_out (float4 grid-stride)
// ---------------------------------------------------------------------------
__global__ void copy_kernel(const float* __restrict__ mem_l,
                            const float* __restrict__ mem_ab,
                            float* __restrict__ out) {
    size_t n4 = (size_t)NBANK * FEAT / 4;   // 32M float4 per bank
    size_t stride = (size_t)gridDim.x * blockDim.x;
    const float4* a  = (const float4*)mem_l;
    const float4* bb = (const float4*)mem_ab;
    float4* ol = (float4*)(out + O_MEML);
    float4* oa = (float4*)(out + O_MEMA);
    for (size_t i = (size_t)blockIdx.x * blockDim.x + threadIdx.x; i < n4; i += stride) {
        ol[i] = a[i];
        oa[i] = bb[i];
    }
}

// ---------------------------------------------------------------------------
// 6) Momentum scatter update (reads ORIGINAL banks, writes into d_out copies)
//    Last-wins on duplicate y to match numpy scatter semantics.
//    grid: BATCH blocks x 64 threads.
// ---------------------------------------------------------------------------
__global__ void update_kernel(const float* __restrict__ mem_l,
                              const float* __restrict__ mem_ab,
                              const int*   __restrict__ y,
                              const float* __restrict__ ws,
                              float* __restrict__ out) {
    int b    = blockIdx.x;
    int lane = threadIdx.x;
    int row  = y[b];
    for (int j = b + 1; j < BATCH; ++j)
        if (y[j] == row) return;              // a later write wins
    // --- bank L ---
    {
        float2 m = ((const float2*)(mem_l + (size_t)row * FEAT))[lane];
        float2 x = ((const float2*)(ws + WS_LN + (size_t)b * FEAT))[lane];
        float2 p = make_float2(m.x * 0.5f + x.x * 0.5f, m.y * 0.5f + x.y * 0.5f);
        float ss = p.x * p.x + p.y * p.y;
        #pragma unroll
        for (int mk = 1; mk < 64; mk <<= 1) ss += __shfl_xor(ss, mk, 64);
        float nrm = sqrtf(ss);
        ((float2*)(out + O_MEML + (size_t)row * FEAT))[lane] =
            make_float2(p.x / nrm, p.y / nrm);
    }
    // --- bank AB ---
    {
        float2 m = ((const float2*)(mem_ab + (size_t)row * FEAT))[lane];
        float2 x = ((const float2*)(ws + WS_ABN + (size_t)b * FEAT))[lane];
        float2 p = make_float2(m.x * 0.5f + x.x * 0.5f, m.y * 0.5f + x.y * 0.5f);
        float ss = p.x * p.x + p.y * p.y;
        #pragma unroll
        for (int mk = 1; mk < 64; mk <<= 1) ss += __shfl_xor(ss, mk, 64);
        float nrm = sqrtf(ss);
        ((float2*)(out + O_MEMA + (size_t)row * FEAT))[lane] =
            make_float2(p.x / nrm, p.y / nrm);
    }
}

// ---------------------------------------------------------------------------
extern "C" void kernel_launch(void* const* d_in, const int* in_sizes, int n_in,
                              void* d_out, int out_size, void* d_ws, size_t ws_size,
                              hipStream_t stream) {
    const float* l      = (const float*)d_in[0];
    const float* ab     = (const float*)d_in[1];
    const float* mem_l  = (const float*)d_in[2];
    const float* mem_ab = (const float*)d_in[3];
    const int*   y      = (const int*)d_in[4];
    const int*   idx    = (const int*)d_in[5];
    float* out = (float*)d_out;
    float* ws  = (float*)d_ws;

    // 1) normalize
    norm_kernel<<<dim3(2 * BATCH), dim3(64), 0, stream>>>(l, ab, ws);
    // 2) score (unscaled P + partials)
    score_kernel<<<dim3(BATCH, NCHUNK), dim3(256), 0, stream>>>(
        mem_l, mem_ab, idx, ws, out, ws + WS_PARTL, ws + WS_PARTA);
    // 3) Z
    zreduce_kernel<<<dim3(1), dim3(256), 0, stream>>>(ws + WS_PARTL, ws + WS_PARTA, ws + WS_INVZ);
    // 4) scale
    scale_kernel<<<dim3(1024), dim3(256), 0, stream>>>(out, ws + WS_INVZ);
    // 5) copy banks
    copy_kernel<<<dim3(2048), dim3(256), 0, stream>>>(mem_l, mem_ab, out);
    // 6) momentum scatter
    update_kernel<<<dim3(BATCH), dim3(64), 0, stream>>>(mem_l, mem_ab, y, ws, out);
}

// Round 3
// 598.022 us; speedup vs baseline: 1.2180x; 1.2180x over previous
//
#include <hip/hip_runtime.h>
#include <math.h>

// Problem constants (match reference)
#define FEAT   128
#define NBANK  1000000
#define KP1    4097            // K_NEG + 1
#define BATCH  256
#define INV_T  2.0f            // 1 / T, T = 0.5
#define EPS_N  1e-7f

// Output layout (floats, concatenated in return order)
constexpr size_t TOTP   = (size_t)BATCH * KP1;        // 1048832 per score output
constexpr size_t O_OUTL = 0;
constexpr size_t O_OUTA = TOTP;                       // 1048832
constexpr size_t O_MEML = 2 * TOTP;                   // 2097664
constexpr size_t O_MEMA = O_MEML + (size_t)NBANK * FEAT; // 130097664

// Scoring tiling
constexpr int KCHUNK = 64;                            // k's per score block (4 waves x 16)
constexpr int NCHUNK = (KP1 + KCHUNK - 1) / KCHUNK;   // 65
constexpr int NPART  = BATCH * NCHUNK;                // 16640 partial-sum slots

// Fused grid: every 9th block is a copy block, rest are score blocks
constexpr int SCOREB = BATCH * NCHUNK;                // 16640
constexpr int COPYB  = SCOREB / 8;                    // 2080
constexpr int TOTB   = SCOREB + COPYB;                // 18720

// Workspace layout (floats)
constexpr size_t WS_LN    = 0;
constexpr size_t WS_ABN   = WS_LN + (size_t)BATCH * FEAT;   // 32768
constexpr size_t WS_PARTL = WS_ABN + (size_t)BATCH * FEAT;  // 65536
constexpr size_t WS_PARTA = WS_PARTL + NPART;               // 82176
constexpr size_t WS_INVZ  = WS_PARTA + NPART;               // 98816 (+2)

// Native clang vector type — required for __builtin_nontemporal_*
typedef float vfloat4 __attribute__((ext_vector_type(4)));

__device__ __forceinline__ vfloat4 nt_load4(const vfloat4* p) {
    return __builtin_nontemporal_load(p);
}
__device__ __forceinline__ void nt_store4(vfloat4* p, vfloat4 v) {
    __builtin_nontemporal_store(v, p);
}

// ---------------------------------------------------------------------------
// 1) L2-normalize l and ab rows:  x / (sqrt(sum x^2) + eps)
// ---------------------------------------------------------------------------
__global__ void norm_kernel(const float* __restrict__ l,
                            const float* __restrict__ ab,
                            float* __restrict__ ws) {
    int b    = blockIdx.x;
    int lane = threadIdx.x;           // 0..63, 2 floats per lane
    const float* src;
    float*       dst;
    if (b < BATCH) { src = l  + (size_t)b * FEAT;            dst = ws + WS_LN  + (size_t)b * FEAT; }
    else           { src = ab + (size_t)(b - BATCH) * FEAT;  dst = ws + WS_ABN + (size_t)(b - BATCH) * FEAT; }
    float2 v = *(const float2*)(src + 2 * lane);
    float  ss = v.x * v.x + v.y * v.y;
    #pragma unroll
    for (int m = 1; m < 64; m <<= 1) ss += __shfl_xor(ss, m, 64);
    float inv = 1.0f / (sqrtf(ss) + EPS_N);
    ((float2*)dst)[lane] = make_float2(v.x * inv, v.y * inv);
}

// ---------------------------------------------------------------------------
// 2) FUSED score + bank-copy kernel.
//    Block role by index: bid % 9 == 8 -> copy (grid-stride float4 stream,
//    non-temporal), else -> score (gather both bank rows at idx[b,k],
//    exp(dot*2), unscaled P + per-block partial sums).
//    Interleaving the two roles keeps HBM saturated: the latency-bound
//    gathers leave BW idle that the streaming copy fills.
// ---------------------------------------------------------------------------
__global__ __launch_bounds__(256) void fused_kernel(
        const float* __restrict__ mem_l, const float* __restrict__ mem_ab,
        const int*   __restrict__ idx,
        const float* __restrict__ ws_in,   // ln/abn
        float* __restrict__ out,
        float* __restrict__ part_l, float* __restrict__ part_ab) {
    int bid = blockIdx.x;
    if ((bid % 9) == 8) {
        // ---- copy role ----
        int cid = bid / 9;                       // 0..COPYB-1
        size_t n4 = (size_t)NBANK * FEAT / 4;    // 32M float4 per bank
        size_t stride = (size_t)COPYB * 256;
        const vfloat4* a  = (const vfloat4*)mem_l;
        const vfloat4* bb = (const vfloat4*)mem_ab;
        vfloat4* ol = (vfloat4*)(out + O_MEML);
        vfloat4* oa = (vfloat4*)(out + O_MEMA);
        for (size_t i = (size_t)cid * 256 + threadIdx.x; i < n4; i += stride) {
            nt_store4(ol + i, nt_load4(a + i));
            nt_store4(oa + i, nt_load4(bb + i));
        }
        return;
    }
    // ---- score role ----
    int sid   = (bid / 9) * 8 + (bid % 9);       // 0..SCOREB-1
    int b     = sid % BATCH;
    int chunk = sid / BATCH;                     // 0..NCHUNK-1
    int wave  = threadIdx.x >> 6;
    int lane  = threadIdx.x & 63;

    float2 lv = *(const float2*)(ws_in + WS_LN  + (size_t)b * FEAT + 2 * lane);
    float2 av = *(const float2*)(ws_in + WS_ABN + (size_t)b * FEAT + 2 * lane);

    float sum_l = 0.f, sum_ab = 0.f;
    int k0 = chunk * KCHUNK + wave * (KCHUNK / 4);
    #pragma unroll 4
    for (int i = 0; i < KCHUNK / 4; ++i) {
        int k = k0 + i;
        if (k >= KP1) break;
        int row = idx[(size_t)b * KP1 + k];
        float2 wa = ((const float2*)(mem_ab + (size_t)row * FEAT))[lane];
        float2 wl = ((const float2*)(mem_l  + (size_t)row * FEAT))[lane];
        float dl  = wa.x * lv.x + wa.y * lv.y;   // -> P_l
        float dab = wl.x * av.x + wl.y * av.y;   // -> P_ab
        #pragma unroll
        for (int m = 1; m < 64; m <<= 1) {
            dl  += __shfl_xor(dl,  m, 64);
            dab += __shfl_xor(dab, m, 64);
        }
        float pl  = expf(dl * INV_T);
        float pab = expf(dab * INV_T);
        if (lane == 0) {
            out[O_OUTL + (size_t)b * KP1 + k] = pl;
            out[O_OUTA + (size_t)b * KP1 + k] = pab;
        }
        sum_l += pl; sum_ab += pab;   // identical across lanes post-reduce
    }
    __shared__ float s[8];
    if (lane == 0) { s[wave] = sum_l; s[4 + wave] = sum_ab; }
    __syncthreads();
    if (threadIdx.x == 0) {
        part_l[(size_t)b * NCHUNK + chunk]  = s[0] + s[1] + s[2] + s[3];
        part_ab[(size_t)b * NCHUNK + chunk] = s[4] + s[5] + s[6] + s[7];
    }
}

// ---------------------------------------------------------------------------
// 3) Deterministic reduction of partials -> 1/Z for both outputs
// ---------------------------------------------------------------------------
__global__ void zreduce_kernel(const float* __restrict__ part_l,
                               const float* __restrict__ part_ab,
                               float* __restrict__ invz) {
    __shared__ float sl[256], sa[256];
    float a = 0.f, b = 0.f;
    for (int i = threadIdx.x; i < NPART; i += 256) { a += part_l[i]; b += part_ab[i]; }
    sl[threadIdx.x] = a; sa[threadIdx.x] = b;
    __syncthreads();
    for (int s = 128; s > 0; s >>= 1) {
        if (threadIdx.x < (unsigned)s) {
            sl[threadIdx.x] += sl[threadIdx.x + s];
            sa[threadIdx.x] += sa[threadIdx.x + s];
        }
        __syncthreads();
    }
    if (threadIdx.x == 0) {
        float count = (float)TOTP;
        // out = P / Z, Z = (sum/count) * NBANK  ->  invZ = count / (sum * NBANK)
        invz[0] = count / (sl[0] * (float)NBANK);
        invz[1] = count / (sa[0] * (float)NBANK);
    }
}

// ---------------------------------------------------------------------------
// 4) Scale both P regions in place by 1/Z
// ---------------------------------------------------------------------------
__global__ void scale_kernel(float* __restrict__ out, const float* __restrict__ invz) {
    float zl = invz[0], za = invz[1];
    size_t stride = (size_t)gridDim.x * blockDim.x;
    for (size_t i = (size_t)blockIdx.x * blockDim.x + threadIdx.x; i < TOTP; i += stride) {
        out[O_OUTL + i] *= zl;
        out[O_OUTA + i] *= za;
    }
}

// ---------------------------------------------------------------------------
// 5) Momentum scatter update (reads ORIGINAL banks, writes into d_out copies)
//    Last-wins on duplicate y to match numpy scatter semantics.
// ---------------------------------------------------------------------------
__global__ void update_kernel(const float* __restrict__ mem_l,
                              const float* __restrict__ mem_ab,
                              const int*   __restrict__ y,
                              const float* __restrict__ ws,
                              float* __restrict__ out) {
    int b    = blockIdx.x;
    int lane = threadIdx.x;
    int row  = y[b];
    for (int j = b + 1; j < BATCH; ++j)
        if (y[j] == row) return;              // a later write wins
    // --- bank L ---
    {
        float2 m = ((const float2*)(mem_l + (size_t)row * FEAT))[lane];
        float2 x = ((const float2*)(ws + WS_LN + (size_t)b * FEAT))[lane];
        float2 p = make_float2(m.x * 0.5f + x.x * 0.5f, m.y * 0.5f + x.y * 0.5f);
        float ss = p.x * p.x + p.y * p.y;
        #pragma unroll
        for (int mk = 1; mk < 64; mk <<= 1) ss += __shfl_xor(ss, mk, 64);
        float nrm = sqrtf(ss);
        ((float2*)(out + O_MEML + (size_t)row * FEAT))[lane] =
            make_float2(p.x / nrm, p.y / nrm);
    }
    // --- bank AB ---
    {
        float2 m = ((const float2*)(mem_ab + (size_t)row * FEAT))[lane];
        float2 x = ((const float2*)(ws + WS_ABN + (size_t)b * FEAT))[lane];
        float2 p = make_float2(m.x * 0.5f + x.x * 0.5f, m.y * 0.5f + x.y * 0.5f);
        float ss = p.x * p.x + p.y * p.y;
        #pragma unroll
        for (int mk = 1; mk < 64; mk <<= 1) ss += __shfl_xor(ss, mk, 64);
        float nrm = sqrtf(ss);
        ((float2*)(out + O_MEMA + (size_t)row * FEAT))[lane] =
            make_float2(p.x / nrm, p.y / nrm);
    }
}

// ---------------------------------------------------------------------------
extern "C" void kernel_launch(void* const* d_in, const int* in_sizes, int n_in,
                              void* d_out, int out_size, void* d_ws, size_t ws_size,
                              hipStream_t stream) {
    const float* l      = (const float*)d_in[0];
    const float* ab     = (const float*)d_in[1];
    const float* mem_l  = (const float*)d_in[2];
    const float* mem_ab = (const float*)d_in[3];
    const int*   y      = (const int*)d_in[4];
    const int*   idx    = (const int*)d_in[5];
    float* out = (float*)d_out;
    float* ws  = (float*)d_ws;

    // 1) normalize
    norm_kernel<<<dim3(2 * BATCH), dim3(64), 0, stream>>>(l, ab, ws);
    // 2) fused score + bank copy
    fused_kernel<<<dim3(TOTB), dim3(256), 0, stream>>>(
        mem_l, mem_ab, idx, ws, out, ws + WS_PARTL, ws + WS_PARTA);
    // 3) Z
    zreduce_kernel<<<dim3(1), dim3(256), 0, stream>>>(ws + WS_PARTL, ws + WS_PARTA, ws + WS_INVZ);
    // 4) scale
    scale_kernel<<<dim3(1024), dim3(256), 0, stream>>>(out, ws + WS_INVZ);
    // 5) momentum scatter (after copy, last-wins)
    update_kernel<<<dim3(BATCH), dim3(64), 0, stream>>>(mem_l, mem_ab, y, ws, out);
}

// Round 4
// 583.212 us; speedup vs baseline: 1.2489x; 1.0254x over previous
//
#include <hip/hip_runtime.h>
#include <math.h>

// Problem constants (match reference)
#define FEAT   128
#define NBANK  1000000
#define KP1    4097            // K_NEG + 1
#define BATCH  256
#define INV_T  2.0f            // 1 / T, T = 0.5
#define EPS_N  1e-7f

// Output layout (floats, concatenated in return order)
constexpr size_t TOTP   = (size_t)BATCH * KP1;        // 1048832 per score output
constexpr size_t O_OUTL = 0;
constexpr size_t O_OUTA = TOTP;                       // 1048832
constexpr size_t O_MEML = 2 * TOTP;                   // 2097664
constexpr size_t O_MEMA = O_MEML + (size_t)NBANK * FEAT; // 130097664

// Scoring tiling: 64 k per block, 16 per wave, 4 per wave-batch (16 lanes/row)
constexpr int KCHUNK = 64;
constexpr int NCHUNK = (KP1 + KCHUNK - 1) / KCHUNK;   // 65
constexpr int NPART  = BATCH * NCHUNK;                // 16640 partial-sum slots
constexpr int SCOREB = BATCH * NCHUNK;                // 16640 blocks

// Copy strip-mining folded into the score loop: 8 slots x (bid*256+tid) stride
constexpr size_t N4      = (size_t)NBANK * FEAT / 4;  // 32M float4 per bank
constexpr size_t CSTRIDE = (size_t)SCOREB * 256;      // 4259840

// Workspace layout (floats)
constexpr size_t WS_LN    = 0;
constexpr size_t WS_ABN   = WS_LN + (size_t)BATCH * FEAT;   // 32768
constexpr size_t WS_PARTL = WS_ABN + (size_t)BATCH * FEAT;  // 65536
constexpr size_t WS_PARTA = WS_PARTL + NPART;               // 82176
constexpr size_t WS_INVZ  = WS_PARTA + NPART;               // 98816 (+2)

// Native clang vector type — required for __builtin_nontemporal_*
typedef float vfloat4 __attribute__((ext_vector_type(4)));

__device__ __forceinline__ void nt_store4(vfloat4* p, vfloat4 v) {
    __builtin_nontemporal_store(v, p);
}
__device__ __forceinline__ float dot4(vfloat4 a, vfloat4 b) {
    return a.x * b.x + a.y * b.y + a.z * b.z + a.w * b.w;
}

// ---------------------------------------------------------------------------
// 1) L2-normalize l and ab rows:  x / (sqrt(sum x^2) + eps)
// ---------------------------------------------------------------------------
__global__ void norm_kernel(const float* __restrict__ l,
                            const float* __restrict__ ab,
                            float* __restrict__ ws) {
    int b    = blockIdx.x;
    int lane = threadIdx.x;           // 0..63, 2 floats per lane
    const float* src;
    float*       dst;
    if (b < BATCH) { src = l  + (size_t)b * FEAT;            dst = ws + WS_LN  + (size_t)b * FEAT; }
    else           { src = ab + (size_t)(b - BATCH) * FEAT;  dst = ws + WS_ABN + (size_t)(b - BATCH) * FEAT; }
    float2 v = *(const float2*)(src + 2 * lane);
    float  ss = v.x * v.x + v.y * v.y;
    #pragma unroll
    for (int m = 1; m < 64; m <<= 1) ss += __shfl_xor(ss, m, 64);
    float inv = 1.0f / (sqrtf(ss) + EPS_N);
    ((float2*)dst)[lane] = make_float2(v.x * inv, v.y * inv);
}

// ---------------------------------------------------------------------------
// 2) FUSED score + bank-copy kernel, one role per block (all blocks equal).
//    Score: 16-lane groups each own one k; a wave gathers 4 rows/bank/batch
//    via dwordx4, reduces with a 4-stage butterfly shared by all 4 k's.
//    Copy: 2 float4 slots per bank folded into each batch iteration — the
//    independent streaming ops fill the gather latency gaps.
// ---------------------------------------------------------------------------
__global__ __launch_bounds__(256) void fused_kernel(
        const float* __restrict__ mem_l, const float* __restrict__ mem_ab,
        const int*   __restrict__ idx,
        const float* __restrict__ ws_in,   // ln/abn
        float* __restrict__ out,
        float* __restrict__ part_l, float* __restrict__ part_ab) {
    int sid    = blockIdx.x;                 // 0..SCOREB-1
    int b      = sid % BATCH;
    int chunk  = sid / BATCH;                // 0..NCHUNK-1
    int wave   = threadIdx.x >> 6;
    int lane   = threadIdx.x & 63;
    int lane16 = lane & 15;                  // position within row (x8 floats)
    int g      = lane >> 4;                  // group = which k of the batch

    // x fragments for this lane's 32B row segment (floats [lane16*8, +8))
    const vfloat4* lnp = (const vfloat4*)(ws_in + WS_LN  + (size_t)b * FEAT);
    const vfloat4* abp = (const vfloat4*)(ws_in + WS_ABN + (size_t)b * FEAT);
    vfloat4 lv0 = lnp[lane16 * 2], lv1 = lnp[lane16 * 2 + 1];
    vfloat4 av0 = abp[lane16 * 2], av1 = abp[lane16 * 2 + 1];

    // copy pointers
    const vfloat4* ca = (const vfloat4*)mem_l;
    const vfloat4* cb = (const vfloat4*)mem_ab;
    vfloat4* ol = (vfloat4*)(out + O_MEML);
    vfloat4* oa = (vfloat4*)(out + O_MEMA);
    size_t cbase = (size_t)sid * 256 + threadIdx.x;

    const int* idx_b = idx + (size_t)b * KP1;
    int kw = chunk * KCHUNK + wave * 16;     // wave's first k

    float sum_l = 0.f, sum_ab = 0.f;
    #pragma unroll
    for (int t = 0; t < 4; ++t) {
        // ---- copy slots 2t, 2t+1 (both banks) ----
        #pragma unroll
        for (int j = 0; j < 2; ++j) {
            size_t ci = cbase + (size_t)(2 * t + j) * CSTRIDE;
            if (ci < N4) {
                nt_store4(ol + ci, ca[ci]);
                nt_store4(oa + ci, cb[ci]);
            }
        }
        // ---- score batch: 4 k's, one per 16-lane group ----
        int k = kw + t * 4 + g;
        bool valid = k < KP1;
        int row = valid ? idx_b[k] : 0;
        const vfloat4* pa = (const vfloat4*)(mem_ab + (size_t)row * FEAT) + lane16 * 2;
        const vfloat4* pw = (const vfloat4*)(mem_l  + (size_t)row * FEAT) + lane16 * 2;
        vfloat4 wa0 = pa[0], wa1 = pa[1];
        vfloat4 wl0 = pw[0], wl1 = pw[1];
        float dl  = dot4(wa0, lv0) + dot4(wa1, lv1);   // -> P_l
        float dab = dot4(wl0, av0) + dot4(wl1, av1);   // -> P_ab
        #pragma unroll
        for (int m = 1; m < 16; m <<= 1) {
            dl  += __shfl_xor(dl,  m, 64);
            dab += __shfl_xor(dab, m, 64);
        }
        float pl  = valid ? __expf(dl  * INV_T) : 0.f;
        float pab = valid ? __expf(dab * INV_T) : 0.f;
        if (lane16 == 0 && valid) {
            out[O_OUTL + (size_t)b * KP1 + k] = pl;
            out[O_OUTA + (size_t)b * KP1 + k] = pab;
        }
        sum_l += pl; sum_ab += pab;          // identical within each 16-group
    }
    // cross-group reduce (4 groups -> wave total on every lane)
    #pragma unroll
    for (int m = 16; m < 64; m <<= 1) {
        sum_l  += __shfl_xor(sum_l,  m, 64);
        sum_ab += __shfl_xor(sum_ab, m, 64);
    }
    __shared__ float s[8];
    if (lane == 0) { s[wave] = sum_l; s[4 + wave] = sum_ab; }
    __syncthreads();
    if (threadIdx.x == 0) {
        part_l[(size_t)b * NCHUNK + chunk]  = s[0] + s[1] + s[2] + s[3];
        part_ab[(size_t)b * NCHUNK + chunk] = s[4] + s[5] + s[6] + s[7];
    }
}

// ---------------------------------------------------------------------------
// 3) Deterministic reduction of partials -> 1/Z for both outputs
// ---------------------------------------------------------------------------
__global__ void zreduce_kernel(const float* __restrict__ part_l,
                               const float* __restrict__ part_ab,
                               float* __restrict__ invz) {
    __shared__ float sl[256], sa[256];
    float a = 0.f, b = 0.f;
    for (int i = threadIdx.x; i < NPART; i += 256) { a += part_l[i]; b += part_ab[i]; }
    sl[threadIdx.x] = a; sa[threadIdx.x] = b;
    __syncthreads();
    for (int s = 128; s > 0; s >>= 1) {
        if (threadIdx.x < (unsigned)s) {
            sl[threadIdx.x] += sl[threadIdx.x + s];
            sa[threadIdx.x] += sa[threadIdx.x + s];
        }
        __syncthreads();
    }
    if (threadIdx.x == 0) {
        float count = (float)TOTP;
        // out = P / Z, Z = (sum/count) * NBANK  ->  invZ = count / (sum * NBANK)
        invz[0] = count / (sl[0] * (float)NBANK);
        invz[1] = count / (sa[0] * (float)NBANK);
    }
}

// ---------------------------------------------------------------------------
// 4) Scale both P regions in place by 1/Z
// ---------------------------------------------------------------------------
__global__ void scale_kernel(float* __restrict__ out, const float* __restrict__ invz) {
    float zl = invz[0], za = invz[1];
    size_t stride = (size_t)gridDim.x * blockDim.x;
    for (size_t i = (size_t)blockIdx.x * blockDim.x + threadIdx.x; i < TOTP; i += stride) {
        out[O_OUTL + i] *= zl;
        out[O_OUTA + i] *= za;
    }
}

// ---------------------------------------------------------------------------
// 5) Momentum scatter update (reads ORIGINAL banks, writes into d_out copies)
//    Last-wins on duplicate y to match numpy scatter semantics.
// ---------------------------------------------------------------------------
__global__ void update_kernel(const float* __restrict__ mem_l,
                              const float* __restrict__ mem_ab,
                              const int*   __restrict__ y,
                              const float* __restrict__ ws,
                              float* __restrict__ out) {
    int b    = blockIdx.x;
    int lane = threadIdx.x;
    int row  = y[b];
    for (int j = b + 1; j < BATCH; ++j)
        if (y[j] == row) return;              // a later write wins
    // --- bank L ---
    {
        float2 m = ((const float2*)(mem_l + (size_t)row * FEAT))[lane];
        float2 x = ((const float2*)(ws + WS_LN + (size_t)b * FEAT))[lane];
        float2 p = make_float2(m.x * 0.5f + x.x * 0.5f, m.y * 0.5f + x.y * 0.5f);
        float ss = p.x * p.x + p.y * p.y;
        #pragma unroll
        for (int mk = 1; mk < 64; mk <<= 1) ss += __shfl_xor(ss, mk, 64);
        float nrm = sqrtf(ss);
        ((float2*)(out + O_MEML + (size_t)row * FEAT))[lane] =
            make_float2(p.x / nrm, p.y / nrm);
    }
    // --- bank AB ---
    {
        float2 m = ((const float2*)(mem_ab + (size_t)row * FEAT))[lane];
        float2 x = ((const float2*)(ws + WS_ABN + (size_t)b * FEAT))[lane];
        float2 p = make_float2(m.x * 0.5f + x.x * 0.5f, m.y * 0.5f + x.y * 0.5f);
        float ss = p.x * p.x + p.y * p.y;
        #pragma unroll
        for (int mk = 1; mk < 64; mk <<= 1) ss += __shfl_xor(ss, mk, 64);
        float nrm = sqrtf(ss);
        ((float2*)(out + O_MEMA + (size_t)row * FEAT))[lane] =
            make_float2(p.x / nrm, p.y / nrm);
    }
}

// ---------------------------------------------------------------------------
extern "C" void kernel_launch(void* const* d_in, const int* in_sizes, int n_in,
                              void* d_out, int out_size, void* d_ws, size_t ws_size,
                              hipStream_t stream) {
    const float* l      = (const float*)d_in[0];
    const float* ab     = (const float*)d_in[1];
    const float* mem_l  = (const float*)d_in[2];
    const float* mem_ab = (const float*)d_in[3];
    const int*   y      = (const int*)d_in[4];
    const int*   idx    = (const int*)d_in[5];
    float* out = (float*)d_out;
    float* ws  = (float*)d_ws;

    // 1) normalize
    norm_kernel<<<dim3(2 * BATCH), dim3(64), 0, stream>>>(l, ab, ws);
    // 2) fused score + bank copy (uniform blocks)
    fused_kernel<<<dim3(SCOREB), dim3(256), 0, stream>>>(
        mem_l, mem_ab, idx, ws, out, ws + WS_PARTL, ws + WS_PARTA);
    // 3) Z
    zreduce_kernel<<<dim3(1), dim3(256), 0, stream>>>(ws + WS_PARTL, ws + WS_PARTA, ws + WS_INVZ);
    // 4) scale
    scale_kernel<<<dim3(1024), dim3(256), 0, stream>>>(out, ws + WS_INVZ);
    // 5) momentum scatter (after copy, last-wins)
    update_kernel<<<dim3(BATCH), dim3(64), 0, stream>>>(mem_l, mem_ab, y, ws, out);
}